// Round 5
// baseline (836.565 us; speedup 1.0000x reference)
//
#include <hip/hip_runtime.h>
#include <math.h>

#define NN 20000
#define EDGES 200000
#define MPAD 20096  // 157*128 — A-side GEMM buffers padded to full tiles

using short8  = __attribute__((ext_vector_type(8))) short;
using short4v = __attribute__((ext_vector_type(4))) short;
using f32x4   = __attribute__((ext_vector_type(4))) float;
typedef unsigned short ushortT;
typedef unsigned int uintT;

__device__ __forceinline__ ushortT f2bfu(float x) {
  union { float f; unsigned u; } c; c.f = x;
  unsigned r = c.u + 0x7FFFu + ((c.u >> 16) & 1u);
  return (ushortT)(r >> 16);
}
__device__ __forceinline__ float bflo(uintT u) {
  union { unsigned i; float f; } c; c.i = u << 16; return c.f;
}
__device__ __forceinline__ float bfhi(uintT u) {
  union { unsigned i; float f; } c; c.i = u & 0xFFFF0000u; return c.f;
}
__device__ __forceinline__ float elu_f(float v) { return v > 0.f ? v : (expf(v) - 1.f); }

__device__ __forceinline__ void acc8(float* acc, uint4 u, float a) {
  acc[0] += a * bflo(u.x); acc[1] += a * bfhi(u.x);
  acc[2] += a * bflo(u.y); acc[3] += a * bfhi(u.y);
  acc[4] += a * bflo(u.z); acc[5] += a * bfhi(u.z);
  acc[6] += a * bflo(u.w); acc[7] += a * bfhi(u.w);
}

// ---------------- CSR build ----------------
__global__ void k_hist(const int* __restrict__ ei, int* __restrict__ cnt) {
  int i = blockIdx.x * 256 + threadIdx.x;
  const int EE = EDGES + NN;
  if (i >= EE) return;
  int d = (i < EDGES) ? ei[EDGES + i] : (i - EDGES);
  atomicAdd(&cnt[d], 1);
}

__global__ __launch_bounds__(256) void k_scan1(const int* __restrict__ cnt,
                                               int* __restrict__ bsum, int n) {
  int b = blockIdx.x, t = threadIdx.x, i = b * 256 + t;
  int v = (i < n) ? cnt[i] : 0;
#pragma unroll
  for (int off = 32; off > 0; off >>= 1) v += __shfl_down(v, off);
  __shared__ int s[4];
  if ((t & 63) == 0) s[t >> 6] = v;
  __syncthreads();
  if (t == 0) bsum[b] = s[0] + s[1] + s[2] + s[3];
}

__global__ void k_scan2(const int* __restrict__ bsum, int* __restrict__ boff,
                        int nb, int* __restrict__ ptr, int n) {
  if (threadIdx.x == 0) {
    int acc = 0;
    for (int b = 0; b < nb; ++b) { boff[b] = acc; acc += bsum[b]; }
    ptr[n] = acc;
  }
}

__global__ __launch_bounds__(256) void k_scan3(const int* __restrict__ cnt,
                                               const int* __restrict__ boff,
                                               int* __restrict__ ptr,
                                               int* __restrict__ cursor, int n) {
  __shared__ int sd[256];
  int b = blockIdx.x, t = threadIdx.x, i = b * 256 + t;
  int v = (i < n) ? cnt[i] : 0;
  sd[t] = v;
  __syncthreads();
  for (int off = 1; off < 256; off <<= 1) {
    int a = (t >= off) ? sd[t - off] : 0;
    __syncthreads();
    sd[t] += a;
    __syncthreads();
  }
  if (i < n) {
    int p = boff[b] + sd[t] - v;  // exclusive
    ptr[i] = p;
    cursor[i] = p;
  }
}

__global__ void k_scatter(const int* __restrict__ ei, int* __restrict__ cursor,
                          int* __restrict__ ssrc) {
  int i = blockIdx.x * 256 + threadIdx.x;
  const int EE = EDGES + NN;
  if (i >= EE) return;
  int s, d;
  if (i < EDGES) { s = ei[i]; d = ei[EDGES + i]; }
  else           { s = i - EDGES; d = s; }
  int pos = atomicAdd(&cursor[d], 1);
  ssrc[pos] = s;
}

// ---------------- weight convert + transpose: W[K][N] f32 -> Wt[N][K] bf16 ----
struct CvtDesc { const float* src; ushortT* dst; int K; int N; int t0; };
struct CvtArgs { CvtDesc d[11]; };

__global__ __launch_bounds__(256) void k_cvtT(CvtArgs a) {
  __shared__ float tile[32][33];
  int b = blockIdx.x;
  int mi = 0;
#pragma unroll
  for (int i = 1; i < 11; ++i)
    if (b >= a.d[i].t0) mi = i;
  CvtDesc dd = a.d[mi];
  int tb = b - dd.t0;
  int tnc = dd.N / 32;
  int tk = tb / tnc, tn = tb % tnc;
  int t = threadIdx.x;
  {
    int r = t >> 3, c4 = (t & 7) * 4;
    float4 v = *reinterpret_cast<const float4*>(&dd.src[(size_t)(tk * 32 + r) * dd.N + tn * 32 + c4]);
    tile[r][c4 + 0] = v.x; tile[r][c4 + 1] = v.y; tile[r][c4 + 2] = v.z; tile[r][c4 + 3] = v.w;
  }
  __syncthreads();
  {
    int n = t >> 3, k4 = (t & 7) * 4;
    short4v s;
    s.x = (short)f2bfu(tile[k4 + 0][n]);
    s.y = (short)f2bfu(tile[k4 + 1][n]);
    s.z = (short)f2bfu(tile[k4 + 2][n]);
    s.w = (short)f2bfu(tile[k4 + 3][n]);
    *reinterpret_cast<short4v*>(&dd.dst[(size_t)(tn * 32 + n) * dd.K + tk * 32 + k4]) = s;
  }
}

// ---------------- x_in fp32 -> bf16 ----------------
__global__ void k_cvtX(const float* __restrict__ in, ushortT* __restrict__ out, int n4) {
  int i = blockIdx.x * 256 + threadIdx.x;
  if (i >= n4) return;
  float4 v = reinterpret_cast<const float4*>(in)[i];
  short4v s;
  s.x = (short)f2bfu(v.x); s.y = (short)f2bfu(v.y);
  s.z = (short)f2bfu(v.z); s.w = (short)f2bfu(v.w);
  reinterpret_cast<short4v*>(out)[i] = s;
}

// ---------------- LayerNorm (D=512), fp32 in -> bf16 out ----------------
__global__ __launch_bounds__(256) void k_ln(const float* __restrict__ in,
                                            const float* __restrict__ g,
                                            const float* __restrict__ b,
                                            ushortT* __restrict__ out) {
  int row = blockIdx.x, t = threadIdx.x;
  const float* r = in + (size_t)row * 512;
  float v0 = r[t], v1 = r[t + 256];
  __shared__ float red[4];
  int w = t >> 6, lane = t & 63;
  float s = v0 + v1;
#pragma unroll
  for (int off = 32; off > 0; off >>= 1) s += __shfl_down(s, off);
  if (lane == 0) red[w] = s;
  __syncthreads();
  float mu = (red[0] + red[1] + red[2] + red[3]) * (1.f / 512.f);
  float d0 = v0 - mu, d1 = v1 - mu;
  float vs = d0 * d0 + d1 * d1;
#pragma unroll
  for (int off = 32; off > 0; off >>= 1) vs += __shfl_down(vs, off);
  __syncthreads();
  if (lane == 0) red[w] = vs;
  __syncthreads();
  float var = (red[0] + red[1] + red[2] + red[3]) * (1.f / 512.f);
  float rs = rsqrtf(var + 1e-5f);
  ushortT* o = out + (size_t)row * 512;
  o[t]       = f2bfu(d0 * rs * g[t]       + b[t]);
  o[t + 256] = f2bfu(d1 * rs * g[t + 256] + b[t + 256]);
}

// ---------------- GEMM: Out[M,N] = A[M,K] @ Wt[N,K]^T  (bf16 MFMA) ----------
// 128x128 tile, 4 waves (2x2), reg double-buffered staging, XCD-affinity grid.
// EPI: 0 = plain, 1 = elu(acc + bias), 2 = elu(res + acc + bias)
// ATT: 0 = none; 1 = fused 6-head attention logits (g1: 4x128ch via w1, g2:
//      2x64ch via w2, split at col 512); 2 = fused 8-head (128ch, w1 only).
//      Epilogue computes s/d dot-products from fp32 acc and atomically
//      accumulates into as_out/ad_out[row*H + head] (pre-zeroed).
//      A 64-col wave strip never crosses a head boundary (128/64-aligned).
template <int EPI, bool OUTBF16, int NB, int ATT>
__global__ __launch_bounds__(256) void k_gemm(const ushortT* __restrict__ A,
                                              const ushortT* __restrict__ Wt,
                                              const float* __restrict__ bias,
                                              const float* __restrict__ res,
                                              void* __restrict__ Outv,
                                              const float* __restrict__ w1s,
                                              const float* __restrict__ w1d,
                                              const float* __restrict__ w2s,
                                              const float* __restrict__ w2d,
                                              float* __restrict__ as_out,
                                              float* __restrict__ ad_out,
                                              int M, int N, int K) {
  __shared__ short As[128][40];
  __shared__ short Bs[128][40];
  int b = blockIdx.x;
  int x = b & 7, g = b >> 3;
  int mt = x + 8 * (g / NB);
  int nt = g % NB;
  int m0 = mt * 128, n0 = nt * 128;
  if (m0 >= M) return;
  int t = threadIdx.x;
  int w = t >> 6, lane = t & 63;
  int wm = w >> 1, wn = w & 1;
  int lr = lane & 15, lk = (lane >> 4) * 8;
  int sr = t >> 2, sc = (t & 3) * 8;   // staging: rows sr, sr+64; k-chunk sc
  int ga0 = m0 + sr, ga1 = m0 + sr + 64;
  const short8 z8 = {};

  short8 vA0, vA1, vB0, vB1;
  {
    vA0 = (ga0 < M) ? *reinterpret_cast<const short8*>(&A[(size_t)ga0 * K + sc]) : z8;
    vA1 = (ga1 < M) ? *reinterpret_cast<const short8*>(&A[(size_t)ga1 * K + sc]) : z8;
    vB0 = *reinterpret_cast<const short8*>(&Wt[(size_t)(n0 + sr) * K + sc]);
    vB1 = *reinterpret_cast<const short8*>(&Wt[(size_t)(n0 + sr + 64) * K + sc]);
  }
  f32x4 acc[4][4] = {};
  for (int k0 = 0; k0 < K; k0 += 32) {
    *reinterpret_cast<short8*>(&As[sr][sc]) = vA0;
    *reinterpret_cast<short8*>(&As[sr + 64][sc]) = vA1;
    *reinterpret_cast<short8*>(&Bs[sr][sc]) = vB0;
    *reinterpret_cast<short8*>(&Bs[sr + 64][sc]) = vB1;
    __syncthreads();
    int k1 = k0 + 32;
    if (k1 < K) {
      vA0 = (ga0 < M) ? *reinterpret_cast<const short8*>(&A[(size_t)ga0 * K + k1 + sc]) : z8;
      vA1 = (ga1 < M) ? *reinterpret_cast<const short8*>(&A[(size_t)ga1 * K + k1 + sc]) : z8;
      vB0 = *reinterpret_cast<const short8*>(&Wt[(size_t)(n0 + sr) * K + k1 + sc]);
      vB1 = *reinterpret_cast<const short8*>(&Wt[(size_t)(n0 + sr + 64) * K + k1 + sc]);
    }
    short8 af[4], bf[4];
#pragma unroll
    for (int m = 0; m < 4; ++m)
      af[m] = *reinterpret_cast<const short8*>(&As[wm * 64 + m * 16 + lr][lk]);
#pragma unroll
    for (int n = 0; n < 4; ++n)
      bf[n] = *reinterpret_cast<const short8*>(&Bs[wn * 64 + n * 16 + lr][lk]);
#pragma unroll
    for (int m = 0; m < 4; ++m)
#pragma unroll
      for (int n = 0; n < 4; ++n)
        acc[m][n] = __builtin_amdgcn_mfma_f32_16x16x32_bf16(af[m], bf[n], acc[m][n], 0, 0, 0);
    __syncthreads();
  }
  // store
#pragma unroll
  for (int m = 0; m < 4; ++m) {
#pragma unroll
    for (int n = 0; n < 4; ++n) {
#pragma unroll
      for (int j = 0; j < 4; ++j) {
        int row = wm * 64 + m * 16 + (lane >> 4) * 4 + j;
        int col = wn * 64 + n * 16 + lr;
        int gr = m0 + row, gc = n0 + col;
        if (gr < M) {
          float v = acc[m][n][j];
          if (EPI >= 1) v += bias[gc];
          if (EPI == 2) v += res[(size_t)gr * N + gc];
          if (EPI >= 1) v = elu_f(v);
          if (OUTBF16) ((ushortT*)Outv)[(size_t)gr * N + gc] = f2bfu(v);
          else         ((float*)Outv)[(size_t)gr * N + gc] = v;
        }
      }
    }
  }
  // fused attention logits
  if (ATT) {
    float wsv[4], wdv[4];
#pragma unroll
    for (int n = 0; n < 4; ++n) {
      int gc = n0 + wn * 64 + n * 16 + lr;
      if (ATT == 1) {
        wsv[n] = (gc < 512) ? w1s[gc] : w2s[gc - 512];
        wdv[n] = (gc < 512) ? w1d[gc] : w2d[gc - 512];
      } else {
        wsv[n] = w1s[gc];
        wdv[n] = w1d[gc];
      }
    }
    int hc = n0 + wn * 64;
    int head = (ATT == 1) ? ((hc < 512) ? (hc >> 7) : 4 + ((hc - 512) >> 6))
                          : (hc >> 7);
    const int H = (ATT == 1) ? 6 : 8;
#pragma unroll
    for (int m = 0; m < 4; ++m) {
#pragma unroll
      for (int j = 0; j < 4; ++j) {
        float sa = 0.f, da = 0.f;
#pragma unroll
        for (int n = 0; n < 4; ++n) {
          float v = acc[m][n][j];
          sa += v * wsv[n];
          da += v * wdv[n];
        }
#pragma unroll
        for (int o = 1; o < 16; o <<= 1) {
          sa += __shfl_xor(sa, o, 16);
          da += __shfl_xor(da, o, 16);
        }
        int gr = m0 + wm * 64 + m * 16 + (lane >> 4) * 4 + j;
        if (lr == 0 && gr < M) {
          atomicAdd(&as_out[gr * H + head], sa);
          atomicAdd(&ad_out[gr * H + head], da);
        }
      }
    }
  }
}

// ---------------- fused aggregate per layer: softmax + gather, 640 ch -------
// Block per dst. Phase A: compute leaky-relu logits for all edges in LDS,
// online max/den per head (H threads), normalize alpha in LDS. Phase B:
// 4 edge-groups x 80 lanes pair-unrolled channel gather. deg<=64 is the
// practical case (Poisson ~10.5); deg>64 handled by strip loop + re-gather.
__global__ __launch_bounds__(320) void k_agg_blk(const ushortT* __restrict__ h,
                                                 const float* __restrict__ as_n,
                                                 const float* __restrict__ ad_n,
                                                 const int* __restrict__ rowptr,
                                                 const int* __restrict__ ssrc,
                                                 const float* __restrict__ b1,
                                                 const float* __restrict__ b2,
                                                 ushortT* __restrict__ out) {
  int dnode = blockIdx.x;
  int t = threadIdx.x;
  int grp = t / 80;         // 0..3 edge group
  int r = t - grp * 80;     // position in row; ch0 = r*8
  int ch0 = r * 8;
  int head = (ch0 < 512) ? (ch0 >> 7) : (4 + ((ch0 - 512) >> 6));
  int e0 = rowptr[dnode], deg = rowptr[dnode + 1] - e0;
  float acc[8] = {};
  __shared__ float s_alpha[64 * 6];
  __shared__ int s_src[64];
  __shared__ float s_part[4][640];
  __shared__ float s_m[6], s_den[6], s_adv[6];
  if (t < 6) { s_m[t] = -INFINITY; s_den[t] = 0.f; s_adv[t] = ad_n[dnode * 6 + t]; }
  __syncthreads();
  // Phase A: softmax stats (online over strips)
  for (int base = 0; base < deg; base += 64) {
    int cnt = min(64, deg - base);
    if (t < cnt) {
      int s = ssrc[e0 + base + t];
      s_src[t] = s;
#pragma unroll
      for (int hh = 0; hh < 6; ++hh) {
        float v = as_n[s * 6 + hh] + s_adv[hh];
        s_alpha[t * 6 + hh] = (v > 0.f) ? v : 0.2f * v;
      }
    }
    __syncthreads();
    if (t < 6) {
      float mx = s_m[t];
      for (int j = 0; j < cnt; ++j) mx = fmaxf(mx, s_alpha[j * 6 + t]);
      float sc = expf(s_m[t] - mx);   // 0 when s_m==-inf
      float ds = 0.f;
      for (int j = 0; j < cnt; ++j) ds += expf(s_alpha[j * 6 + t] - mx);
      s_den[t] = s_den[t] * sc + ds;
      s_m[t] = mx;
    }
    __syncthreads();
  }
  if (t < 6) s_den[t] = 1.f / s_den[t];
  __syncthreads();
  // Phase B: per strip, normalized alpha then channel gather
  for (int base = 0; base < deg; base += 64) {
    int cnt = min(64, deg - base);
    bool regather = (base > 0) || (deg > 64);
    if (regather) {
      __syncthreads();
      if (t < cnt) {
        int s = ssrc[e0 + base + t];
        s_src[t] = s;
#pragma unroll
        for (int hh = 0; hh < 6; ++hh) {
          float v = as_n[s * 6 + hh] + s_adv[hh];
          s_alpha[t * 6 + hh] = (v > 0.f) ? v : 0.2f * v;
        }
      }
      __syncthreads();
    }
    if (t < cnt) {
#pragma unroll
      for (int hh = 0; hh < 6; ++hh)
        s_alpha[t * 6 + hh] = expf(s_alpha[t * 6 + hh] - s_m[hh]) * s_den[hh];
    }
    __syncthreads();
    int jj = grp;
    for (; jj + 4 < cnt; jj += 8) {
      int sA = s_src[jj], sB = s_src[jj + 4];
      uint4 uA = *reinterpret_cast<const uint4*>(h + (size_t)sA * 640 + ch0);
      uint4 uB = *reinterpret_cast<const uint4*>(h + (size_t)sB * 640 + ch0);
      acc8(acc, uA, s_alpha[jj * 6 + head]);
      acc8(acc, uB, s_alpha[(jj + 4) * 6 + head]);
    }
    if (jj < cnt) {
      int sA = s_src[jj];
      uint4 uA = *reinterpret_cast<const uint4*>(h + (size_t)sA * 640 + ch0);
      acc8(acc, uA, s_alpha[jj * 6 + head]);
    }
  }
  __syncthreads();
#pragma unroll
  for (int q = 0; q < 8; ++q) s_part[grp][ch0 + q] = acc[q];
  __syncthreads();
  {
    int ch = t * 2;
    float v0 = s_part[0][ch] + s_part[1][ch] + s_part[2][ch] + s_part[3][ch];
    float v1 = s_part[0][ch + 1] + s_part[1][ch + 1] + s_part[2][ch + 1] + s_part[3][ch + 1];
    v0 += (ch < 512) ? b1[ch] : b2[ch - 512];
    v1 += (ch < 512) ? b1[ch + 1] : b2[ch - 511];
    v0 = elu_f(v0); v1 = elu_f(v1);
    uintT o = (uintT)f2bfu(v0) | ((uintT)f2bfu(v1) << 16);
    *reinterpret_cast<uintT*>(&out[(size_t)dnode * 640 + ch]) = o;
  }
}

// ---------------- fused aggregate final: softmax + gather, mean 8 heads -----
__global__ __launch_bounds__(256) void k_agg_mean(
    const ushortT* __restrict__ h, const float* __restrict__ as_n,
    const float* __restrict__ ad_n,
    const int* __restrict__ rowptr, const int* __restrict__ ssrc,
    const float* __restrict__ bias, float* __restrict__ out) {
  int dnode = blockIdx.x;
  int t = threadIdx.x;
  int grp = t >> 7;        // 0..1 edge group
  int r = t & 127;         // position in row; ch0 = r*8
  int head = r >> 4;
  int e0 = rowptr[dnode], deg = rowptr[dnode + 1] - e0;
  float acc[8] = {};
  __shared__ float s_alpha[64 * 8];
  __shared__ int s_src[64];
  __shared__ float s_part[2][1024];
  __shared__ float s_m[8], s_den[8], s_adv[8];
  if (t < 8) { s_m[t] = -INFINITY; s_den[t] = 0.f; s_adv[t] = ad_n[dnode * 8 + t]; }
  __syncthreads();
  // Phase A: softmax stats
  for (int base = 0; base < deg; base += 64) {
    int cnt = min(64, deg - base);
    if (t < cnt) {
      int s = ssrc[e0 + base + t];
      s_src[t] = s;
#pragma unroll
      for (int hh = 0; hh < 8; ++hh) {
        float v = as_n[s * 8 + hh] + s_adv[hh];
        s_alpha[t * 8 + hh] = (v > 0.f) ? v : 0.2f * v;
      }
    }
    __syncthreads();
    if (t < 8) {
      float mx = s_m[t];
      for (int j = 0; j < cnt; ++j) mx = fmaxf(mx, s_alpha[j * 8 + t]);
      float sc = expf(s_m[t] - mx);
      float ds = 0.f;
      for (int j = 0; j < cnt; ++j) ds += expf(s_alpha[j * 8 + t] - mx);
      s_den[t] = s_den[t] * sc + ds;
      s_m[t] = mx;
    }
    __syncthreads();
  }
  if (t < 8) s_den[t] = 1.f / s_den[t];
  __syncthreads();
  // Phase B
  for (int base = 0; base < deg; base += 64) {
    int cnt = min(64, deg - base);
    bool regather = (base > 0) || (deg > 64);
    if (regather) {
      __syncthreads();
      if (t < cnt) {
        int s = ssrc[e0 + base + t];
        s_src[t] = s;
#pragma unroll
        for (int hh = 0; hh < 8; ++hh) {
          float v = as_n[s * 8 + hh] + s_adv[hh];
          s_alpha[t * 8 + hh] = (v > 0.f) ? v : 0.2f * v;
        }
      }
      __syncthreads();
    }
    if (t < cnt) {
#pragma unroll
      for (int hh = 0; hh < 8; ++hh)
        s_alpha[t * 8 + hh] = expf(s_alpha[t * 8 + hh] - s_m[hh]) * s_den[hh];
    }
    __syncthreads();
    int jj = grp;
    for (; jj + 2 < cnt; jj += 4) {
      int sA = s_src[jj], sB = s_src[jj + 2];
      uint4 uA = *reinterpret_cast<const uint4*>(h + (size_t)sA * 1024 + r * 8);
      uint4 uB = *reinterpret_cast<const uint4*>(h + (size_t)sB * 1024 + r * 8);
      acc8(acc, uA, s_alpha[jj * 8 + head]);
      acc8(acc, uB, s_alpha[(jj + 2) * 8 + head]);
    }
    if (jj < cnt) {
      int sA = s_src[jj];
      uint4 uA = *reinterpret_cast<const uint4*>(h + (size_t)sA * 1024 + r * 8);
      acc8(acc, uA, s_alpha[jj * 8 + head]);
    }
  }
  __syncthreads();
#pragma unroll
  for (int q = 0; q < 8; ++q) s_part[grp][r * 8 + q] = acc[q];
  __syncthreads();
  if (t < 128) {
    float v = 0.f;
#pragma unroll
    for (int hh = 0; hh < 8; ++hh)
      v += s_part[0][hh * 128 + t] + s_part[1][hh * 128 + t];
    out[(size_t)dnode * 128 + t] = v * 0.125f + bias[t];
  }
}

// ---------------- launch ----------------
extern "C" void kernel_launch(void* const* d_in, const int* in_sizes, int n_in,
                              void* d_out, int out_size, void* d_ws, size_t ws_size,
                              hipStream_t stream) {
  const float* x_in   = (const float*)d_in[0];
  const int*   ei     = (const int*)d_in[1];
  const float* proj_W = (const float*)d_in[2];
  const float* proj_b = (const float*)d_in[3];
  const float* bng    = (const float*)d_in[4];
  const float* bnb    = (const float*)d_in[5];
  const float* g1W    = (const float*)d_in[6];
  const float* g1as   = (const float*)d_in[7];
  const float* g1ad   = (const float*)d_in[8];
  const float* g1b    = (const float*)d_in[9];
  const float* g2W    = (const float*)d_in[10];
  const float* g2as   = (const float*)d_in[11];
  const float* g2ad   = (const float*)d_in[12];
  const float* g2b    = (const float*)d_in[13];
  const float* uniW   = (const float*)d_in[14];
  const float* unib   = (const float*)d_in[15];
  const float* fing   = (const float*)d_in[16];
  const float* finb   = (const float*)d_in[17];
  const float* fgW    = (const float*)d_in[18];
  const float* fgas   = (const float*)d_in[19];
  const float* fgad   = (const float*)d_in[20];
  const float* fgb    = (const float*)d_in[21];

  const int EE = EDGES + NN;
  char* ws = (char*)d_ws;
  size_t off = 0;
  auto alloc = [&](size_t bytes) -> void* {
    void* p = ws + off;
    off += (bytes + 255) & ~(size_t)255;
    return p;
  };
  float*   xA    = (float*)alloc((size_t)NN * 512 * 4);
  float*   xB    = (float*)alloc((size_t)NN * 512 * 4);
  ushortT* xn    = (ushortT*)alloc((size_t)MPAD * 512 * 2);
  ushortT* xinb  = (ushortT*)alloc((size_t)MPAD * 256 * 2);
  ushortT* hcat  = (ushortT*)alloc((size_t)NN * 640 * 2);     // g1|g2 outputs [N,640]
  ushortT* xc    = (ushortT*)alloc((size_t)MPAD * 640 * 2);   // o1|o2 [N,640]
  float*   asb   = (float*)alloc((size_t)NN * 8 * 4);         // 640000 B, 256-aligned
  float*   adb   = (float*)alloc((size_t)NN * 8 * 4);         // contiguous after asb
  ushortT* projT = (ushortT*)alloc((size_t)512 * 256 * 2);
  ushortT* gcatT = (ushortT*)alloc((size_t)3 * 640 * 512 * 2);  // [640][512] per block
  ushortT* uniT  = (ushortT*)alloc((size_t)3 * 512 * 640 * 2);
  ushortT* fgT   = (ushortT*)alloc((size_t)1024 * 512 * 2);
  int* cnt    = (int*)alloc((size_t)NN * 4);
  int* ptr    = (int*)alloc((size_t)(NN + 1) * 4);
  int* cursor = (int*)alloc((size_t)NN * 4);
  int* ssrc   = (int*)alloc((size_t)EE * 4);
  int* bsum   = (int*)alloc((size_t)128 * 4);
  int* boff   = (int*)alloc((size_t)128 * 4);
  ushortT* hf = hcat;  // final [N,1024] bf16 = 41 MB aliases hcat+xc (51.4 MB)

  const int NB79 = (NN + 255) / 256;  // 79

  // CSR build
  hipMemsetAsync(cnt, 0, (size_t)NN * 4, stream);
  k_hist<<<(EE + 255) / 256, 256, 0, stream>>>(ei, cnt);
  k_scan1<<<NB79, 256, 0, stream>>>(cnt, bsum, NN);
  k_scan2<<<1, 64, 0, stream>>>(bsum, boff, NB79, ptr, NN);
  k_scan3<<<NB79, 256, 0, stream>>>(cnt, boff, ptr, cursor, NN);
  k_scatter<<<(EE + 255) / 256, 256, 0, stream>>>(ei, cursor, ssrc);

  // weight transpose+convert (g1|g2 fused into gcatT rows 0..511 | 512..639)
  {
    CvtArgs a;
    int t0 = 0;
    auto add = [&](int idx, const float* s, ushortT* d, int K, int N) {
      a.d[idx] = { s, d, K, N, t0 };
      t0 += (K / 32) * (N / 32);
    };
    add(0, proj_W, projT, 256, 512);
    for (int i = 0; i < 3; ++i)
      add(1 + i, g1W + (size_t)i * 512 * 512, gcatT + (size_t)i * 640 * 512, 512, 512);
    for (int i = 0; i < 3; ++i)
      add(4 + i, g2W + (size_t)i * 512 * 128, gcatT + (size_t)i * 640 * 512 + 512 * 512, 512, 128);
    for (int i = 0; i < 3; ++i)
      add(7 + i, uniW + (size_t)i * 640 * 512, uniT + (size_t)i * 512 * 640, 640, 512);
    add(10, fgW, fgT, 512, 1024);
    k_cvtT<<<t0, 256, 0, stream>>>(a);
  }
  k_cvtX<<<(NN * 256 / 4 + 255) / 256, 256, 0, stream>>>(x_in, xinb, NN * 256 / 4);

  const int GMP = 160;  // padded m-tiles (157 real)

  // proj: x = elu(x_in @ proj_W + proj_b)
  k_gemm<1, false, 4, 0><<<GMP * 4, 256, 0, stream>>>(
      xinb, projT, proj_b, nullptr, xA,
      nullptr, nullptr, nullptr, nullptr, nullptr, nullptr, NN, 512, 256);

  float* cur = xA;
  float* alt = xB;
  for (int i = 0; i < 3; ++i) {
    k_ln<<<NN, 256, 0, stream>>>(cur, bng + i * 512, bnb + i * 512, xn);
    hipMemsetAsync(asb, 0, (size_t)2 * NN * 8 * 4, stream);  // asb|adb contiguous
    // fused g1|g2 GEMM -> hcat [N,640] + attention logits into asb/adb
    k_gemm<0, true, 5, 1><<<GMP * 5, 256, 0, stream>>>(
        xn, gcatT + (size_t)i * 640 * 512, nullptr, nullptr, hcat,
        g1as + i * 512, g1ad + i * 512, g2as + i * 128, g2ad + i * 128,
        asb, adb, NN, 640, 512);
    // fused softmax + aggregate
    k_agg_blk<<<NN, 320, 0, stream>>>(hcat, asb, adb, ptr, ssrc,
                                      g1b + i * 512, g2b + i * 128, xc);
    // x = elu(res + xc @ uniW + unib)
    k_gemm<2, false, 4, 0><<<GMP * 4, 256, 0, stream>>>(
        xc, uniT + (size_t)i * 512 * 640, unib + i * 512, cur, alt,
        nullptr, nullptr, nullptr, nullptr, nullptr, nullptr, NN, 512, 640);
    float* tmp = cur; cur = alt; alt = tmp;
  }

  // final LN + GAT (heads=8, mean)
  k_ln<<<NN, 256, 0, stream>>>(cur, fing, finb, xn);
  hipMemsetAsync(asb, 0, (size_t)2 * NN * 8 * 4, stream);
  k_gemm<0, true, 8, 2><<<GMP * 8, 256, 0, stream>>>(
      xn, fgT, nullptr, nullptr, hf,
      fgas, fgad, nullptr, nullptr, asb, adb, NN, 1024, 512);
  k_agg_mean<<<NN, 256, 0, stream>>>(hf, asb, adb, ptr, ssrc, fgb, (float*)d_out);
}

// Round 6
// 758.765 us; speedup vs baseline: 1.1025x; 1.1025x over previous
//
#include <hip/hip_runtime.h>
#include <math.h>

#define NN 20000
#define EDGES 200000
#define MPAD 20096  // 157*128 — A-side GEMM buffers padded to full tiles

using short8  = __attribute__((ext_vector_type(8))) short;
using short4v = __attribute__((ext_vector_type(4))) short;
using f32x4   = __attribute__((ext_vector_type(4))) float;
typedef unsigned short ushortT;
typedef unsigned int uintT;

__device__ __forceinline__ ushortT f2bfu(float x) {
  union { float f; unsigned u; } c; c.f = x;
  unsigned r = c.u + 0x7FFFu + ((c.u >> 16) & 1u);
  return (ushortT)(r >> 16);
}
__device__ __forceinline__ float bflo(uintT u) {
  union { unsigned i; float f; } c; c.i = u << 16; return c.f;
}
__device__ __forceinline__ float bfhi(uintT u) {
  union { unsigned i; float f; } c; c.i = u & 0xFFFF0000u; return c.f;
}
__device__ __forceinline__ float elu_f(float v) { return v > 0.f ? v : (expf(v) - 1.f); }

__device__ __forceinline__ void acc8(float* acc, uint4 u, float a) {
  acc[0] += a * bflo(u.x); acc[1] += a * bfhi(u.x);
  acc[2] += a * bflo(u.y); acc[3] += a * bfhi(u.y);
  acc[4] += a * bflo(u.z); acc[5] += a * bfhi(u.z);
  acc[6] += a * bflo(u.w); acc[7] += a * bfhi(u.w);
}

// ---------------- CSR build ----------------
__global__ void k_hist(const int* __restrict__ ei, int* __restrict__ cnt) {
  int i = blockIdx.x * 256 + threadIdx.x;
  const int EE = EDGES + NN;
  if (i >= EE) return;
  int d = (i < EDGES) ? ei[EDGES + i] : (i - EDGES);
  atomicAdd(&cnt[d], 1);
}

__global__ __launch_bounds__(256) void k_scan1(const int* __restrict__ cnt,
                                               int* __restrict__ bsum, int n) {
  int b = blockIdx.x, t = threadIdx.x, i = b * 256 + t;
  int v = (i < n) ? cnt[i] : 0;
#pragma unroll
  for (int off = 32; off > 0; off >>= 1) v += __shfl_down(v, off);
  __shared__ int s[4];
  if ((t & 63) == 0) s[t >> 6] = v;
  __syncthreads();
  if (t == 0) bsum[b] = s[0] + s[1] + s[2] + s[3];
}

__global__ void k_scan2(const int* __restrict__ bsum, int* __restrict__ boff,
                        int nb, int* __restrict__ ptr, int n) {
  if (threadIdx.x == 0) {
    int acc = 0;
    for (int b = 0; b < nb; ++b) { boff[b] = acc; acc += bsum[b]; }
    ptr[n] = acc;
  }
}

__global__ __launch_bounds__(256) void k_scan3(const int* __restrict__ cnt,
                                               const int* __restrict__ boff,
                                               int* __restrict__ ptr,
                                               int* __restrict__ cursor, int n) {
  __shared__ int sd[256];
  int b = blockIdx.x, t = threadIdx.x, i = b * 256 + t;
  int v = (i < n) ? cnt[i] : 0;
  sd[t] = v;
  __syncthreads();
  for (int off = 1; off < 256; off <<= 1) {
    int a = (t >= off) ? sd[t - off] : 0;
    __syncthreads();
    sd[t] += a;
    __syncthreads();
  }
  if (i < n) {
    int p = boff[b] + sd[t] - v;  // exclusive
    ptr[i] = p;
    cursor[i] = p;
  }
}

__global__ void k_scatter(const int* __restrict__ ei, int* __restrict__ cursor,
                          int* __restrict__ ssrc) {
  int i = blockIdx.x * 256 + threadIdx.x;
  const int EE = EDGES + NN;
  if (i >= EE) return;
  int s, d;
  if (i < EDGES) { s = ei[i]; d = ei[EDGES + i]; }
  else           { s = i - EDGES; d = s; }
  int pos = atomicAdd(&cursor[d], 1);
  ssrc[pos] = s;
}

// ---------------- weight convert + transpose: W[K][N] f32 -> Wt[N][K] bf16 ----
struct CvtDesc { const float* src; ushortT* dst; int K; int N; int t0; };
struct CvtArgs { CvtDesc d[11]; };

__global__ __launch_bounds__(256) void k_cvtT(CvtArgs a) {
  __shared__ float tile[32][33];
  int b = blockIdx.x;
  int mi = 0;
#pragma unroll
  for (int i = 1; i < 11; ++i)
    if (b >= a.d[i].t0) mi = i;
  CvtDesc dd = a.d[mi];
  int tb = b - dd.t0;
  int tnc = dd.N / 32;
  int tk = tb / tnc, tn = tb % tnc;
  int t = threadIdx.x;
  {
    int r = t >> 3, c4 = (t & 7) * 4;
    float4 v = *reinterpret_cast<const float4*>(&dd.src[(size_t)(tk * 32 + r) * dd.N + tn * 32 + c4]);
    tile[r][c4 + 0] = v.x; tile[r][c4 + 1] = v.y; tile[r][c4 + 2] = v.z; tile[r][c4 + 3] = v.w;
  }
  __syncthreads();
  {
    int n = t >> 3, k4 = (t & 7) * 4;
    short4v s;
    s.x = (short)f2bfu(tile[k4 + 0][n]);
    s.y = (short)f2bfu(tile[k4 + 1][n]);
    s.z = (short)f2bfu(tile[k4 + 2][n]);
    s.w = (short)f2bfu(tile[k4 + 3][n]);
    *reinterpret_cast<short4v*>(&dd.dst[(size_t)(tn * 32 + n) * dd.K + tk * 32 + k4]) = s;
  }
}

// ---------------- x_in fp32 -> bf16 ----------------
__global__ void k_cvtX(const float* __restrict__ in, ushortT* __restrict__ out, int n4) {
  int i = blockIdx.x * 256 + threadIdx.x;
  if (i >= n4) return;
  float4 v = reinterpret_cast<const float4*>(in)[i];
  short4v s;
  s.x = (short)f2bfu(v.x); s.y = (short)f2bfu(v.y);
  s.z = (short)f2bfu(v.z); s.w = (short)f2bfu(v.w);
  reinterpret_cast<short4v*>(out)[i] = s;
}

// ---------------- LayerNorm (D=512), fp32 in -> bf16 out ----------------
__global__ __launch_bounds__(256) void k_ln(const float* __restrict__ in,
                                            const float* __restrict__ g,
                                            const float* __restrict__ b,
                                            ushortT* __restrict__ out) {
  int row = blockIdx.x, t = threadIdx.x;
  const float* r = in + (size_t)row * 512;
  float v0 = r[t], v1 = r[t + 256];
  __shared__ float red[4];
  int w = t >> 6, lane = t & 63;
  float s = v0 + v1;
#pragma unroll
  for (int off = 32; off > 0; off >>= 1) s += __shfl_down(s, off);
  if (lane == 0) red[w] = s;
  __syncthreads();
  float mu = (red[0] + red[1] + red[2] + red[3]) * (1.f / 512.f);
  float d0 = v0 - mu, d1 = v1 - mu;
  float vs = d0 * d0 + d1 * d1;
#pragma unroll
  for (int off = 32; off > 0; off >>= 1) vs += __shfl_down(vs, off);
  __syncthreads();
  if (lane == 0) red[w] = vs;
  __syncthreads();
  float var = (red[0] + red[1] + red[2] + red[3]) * (1.f / 512.f);
  float rs = rsqrtf(var + 1e-5f);
  ushortT* o = out + (size_t)row * 512;
  o[t]       = f2bfu(d0 * rs * g[t]       + b[t]);
  o[t + 256] = f2bfu(d1 * rs * g[t + 256] + b[t + 256]);
}

// ---------------- GEMM: Out[M,N] = A[M,K] @ Wt[N,K]^T  (bf16 MFMA) ----------
// 128x128 tile, 4 waves (2x2), reg double-buffered staging, XCD-affinity grid.
// EPI: 0 = plain, 1 = elu(acc + bias), 2 = elu(res + acc + bias)
// ATT: 0 = none; 1 = fused 6-head attention logits (g1: 4x128ch via w1, g2:
//      2x64ch via w2, split at col 512); 2 = fused 8-head (128ch, w1 only).
//      (verified correct in round 5 — eliminates the k_att* h re-read passes)
template <int EPI, bool OUTBF16, int NB, int ATT>
__global__ __launch_bounds__(256) void k_gemm(const ushortT* __restrict__ A,
                                              const ushortT* __restrict__ Wt,
                                              const float* __restrict__ bias,
                                              const float* __restrict__ res,
                                              void* __restrict__ Outv,
                                              const float* __restrict__ w1s,
                                              const float* __restrict__ w1d,
                                              const float* __restrict__ w2s,
                                              const float* __restrict__ w2d,
                                              float* __restrict__ as_out,
                                              float* __restrict__ ad_out,
                                              int M, int N, int K) {
  __shared__ short As[128][40];
  __shared__ short Bs[128][40];
  int b = blockIdx.x;
  int x = b & 7, g = b >> 3;
  int mt = x + 8 * (g / NB);
  int nt = g % NB;
  int m0 = mt * 128, n0 = nt * 128;
  if (m0 >= M) return;
  int t = threadIdx.x;
  int w = t >> 6, lane = t & 63;
  int wm = w >> 1, wn = w & 1;
  int lr = lane & 15, lk = (lane >> 4) * 8;
  int sr = t >> 2, sc = (t & 3) * 8;   // staging: rows sr, sr+64; k-chunk sc
  int ga0 = m0 + sr, ga1 = m0 + sr + 64;
  const short8 z8 = {};

  short8 vA0, vA1, vB0, vB1;
  {
    vA0 = (ga0 < M) ? *reinterpret_cast<const short8*>(&A[(size_t)ga0 * K + sc]) : z8;
    vA1 = (ga1 < M) ? *reinterpret_cast<const short8*>(&A[(size_t)ga1 * K + sc]) : z8;
    vB0 = *reinterpret_cast<const short8*>(&Wt[(size_t)(n0 + sr) * K + sc]);
    vB1 = *reinterpret_cast<const short8*>(&Wt[(size_t)(n0 + sr + 64) * K + sc]);
  }
  f32x4 acc[4][4] = {};
  for (int k0 = 0; k0 < K; k0 += 32) {
    *reinterpret_cast<short8*>(&As[sr][sc]) = vA0;
    *reinterpret_cast<short8*>(&As[sr + 64][sc]) = vA1;
    *reinterpret_cast<short8*>(&Bs[sr][sc]) = vB0;
    *reinterpret_cast<short8*>(&Bs[sr + 64][sc]) = vB1;
    __syncthreads();
    int k1 = k0 + 32;
    if (k1 < K) {
      vA0 = (ga0 < M) ? *reinterpret_cast<const short8*>(&A[(size_t)ga0 * K + k1 + sc]) : z8;
      vA1 = (ga1 < M) ? *reinterpret_cast<const short8*>(&A[(size_t)ga1 * K + k1 + sc]) : z8;
      vB0 = *reinterpret_cast<const short8*>(&Wt[(size_t)(n0 + sr) * K + k1 + sc]);
      vB1 = *reinterpret_cast<const short8*>(&Wt[(size_t)(n0 + sr + 64) * K + k1 + sc]);
    }
    short8 af[4], bf[4];
#pragma unroll
    for (int m = 0; m < 4; ++m)
      af[m] = *reinterpret_cast<const short8*>(&As[wm * 64 + m * 16 + lr][lk]);
#pragma unroll
    for (int n = 0; n < 4; ++n)
      bf[n] = *reinterpret_cast<const short8*>(&Bs[wn * 64 + n * 16 + lr][lk]);
#pragma unroll
    for (int m = 0; m < 4; ++m)
#pragma unroll
      for (int n = 0; n < 4; ++n)
        acc[m][n] = __builtin_amdgcn_mfma_f32_16x16x32_bf16(af[m], bf[n], acc[m][n], 0, 0, 0);
    __syncthreads();
  }
  // store
#pragma unroll
  for (int m = 0; m < 4; ++m) {
#pragma unroll
    for (int n = 0; n < 4; ++n) {
#pragma unroll
      for (int j = 0; j < 4; ++j) {
        int row = wm * 64 + m * 16 + (lane >> 4) * 4 + j;
        int col = wn * 64 + n * 16 + lr;
        int gr = m0 + row, gc = n0 + col;
        if (gr < M) {
          float v = acc[m][n][j];
          if (EPI >= 1) v += bias[gc];
          if (EPI == 2) v += res[(size_t)gr * N + gc];
          if (EPI >= 1) v = elu_f(v);
          if (OUTBF16) ((ushortT*)Outv)[(size_t)gr * N + gc] = f2bfu(v);
          else         ((float*)Outv)[(size_t)gr * N + gc] = v;
        }
      }
    }
  }
  // fused attention logits
  if (ATT) {
    float wsv[4], wdv[4];
#pragma unroll
    for (int n = 0; n < 4; ++n) {
      int gc = n0 + wn * 64 + n * 16 + lr;
      if (ATT == 1) {
        wsv[n] = (gc < 512) ? w1s[gc] : w2s[gc - 512];
        wdv[n] = (gc < 512) ? w1d[gc] : w2d[gc - 512];
      } else {
        wsv[n] = w1s[gc];
        wdv[n] = w1d[gc];
      }
    }
    int hc = n0 + wn * 64;
    int head = (ATT == 1) ? ((hc < 512) ? (hc >> 7) : 4 + ((hc - 512) >> 6))
                          : (hc >> 7);
    const int H = (ATT == 1) ? 6 : 8;
#pragma unroll
    for (int m = 0; m < 4; ++m) {
#pragma unroll
      for (int j = 0; j < 4; ++j) {
        float sa = 0.f, da = 0.f;
#pragma unroll
        for (int n = 0; n < 4; ++n) {
          float v = acc[m][n][j];
          sa += v * wsv[n];
          da += v * wdv[n];
        }
#pragma unroll
        for (int o = 1; o < 16; o <<= 1) {
          sa += __shfl_xor(sa, o, 16);
          da += __shfl_xor(da, o, 16);
        }
        int gr = m0 + wm * 64 + m * 16 + (lane >> 4) * 4 + j;
        if (lr == 0 && gr < M) {
          atomicAdd(&as_out[gr * H + head], sa);
          atomicAdd(&ad_out[gr * H + head], da);
        }
      }
    }
  }
}

// ---------------- per-dst softmax -> unnormalized exp + 1/den --------------
// 4 nodes/wave, 16 nodes/block; 16-lane-parallel (round-3 structure).
template <int H>
__global__ __launch_bounds__(256) void k_soft16(const float* __restrict__ as_n,
                                                const float* __restrict__ ad_n,
                                                const int* __restrict__ rowptr,
                                                const int* __restrict__ ssrc,
                                                float* __restrict__ alpha,
                                                float* __restrict__ rden_out) {
  int t = threadIdx.x;
  int grp16 = t >> 4;       // 0..15 within block
  int l = t & 15;
  int dnode = blockIdx.x * 16 + grp16;
  int e0 = rowptr[dnode], deg = rowptr[dnode + 1] - e0;
  float adv[H], m[H], den[H];
#pragma unroll
  for (int hh = 0; hh < H; ++hh) {
    adv[hh] = ad_n[dnode * H + hh];
    m[hh] = -INFINITY;
    den[hh] = 0.f;
  }
  // pass 1: per-head max
  for (int base = 0; base < deg; base += 16) {
    int j = base + l;
    float e[H];
    if (j < deg) {
      int s = ssrc[e0 + j];
#pragma unroll
      for (int hh = 0; hh < H; ++hh) {
        float v = as_n[s * H + hh] + adv[hh];
        e[hh] = v > 0.f ? v : 0.2f * v;
      }
    } else {
#pragma unroll
      for (int hh = 0; hh < H; ++hh) e[hh] = -INFINITY;
    }
#pragma unroll
    for (int hh = 0; hh < H; ++hh) {
      float v = e[hh];
#pragma unroll
      for (int o = 8; o > 0; o >>= 1) v = fmaxf(v, __shfl_xor(v, o, 16));
      m[hh] = fmaxf(m[hh], v);
    }
  }
  // pass 2: exp + den, store exp to alpha (unnormalized)
  for (int base = 0; base < deg; base += 16) {
    int j = base + l;
    float p[H];
    if (j < deg) {
      int s = ssrc[e0 + j];
#pragma unroll
      for (int hh = 0; hh < H; ++hh) {
        float v = as_n[s * H + hh] + adv[hh];
        v = v > 0.f ? v : 0.2f * v;
        p[hh] = expf(v - m[hh]);
        alpha[(size_t)(e0 + j) * H + hh] = p[hh];
      }
    } else {
#pragma unroll
      for (int hh = 0; hh < H; ++hh) p[hh] = 0.f;
    }
#pragma unroll
    for (int hh = 0; hh < H; ++hh) {
      float v = p[hh];
#pragma unroll
      for (int o = 8; o > 0; o >>= 1) v += __shfl_xor(v, o, 16);
      den[hh] += v;
    }
  }
  if (l == 0) {
#pragma unroll
    for (int hh = 0; hh < H; ++hh)
      rden_out[dnode * H + hh] = 1.f / den[hh];
  }
}

// ---------------- fused per-layer aggregate: 640 ch, 6 heads, elu ----------
// 4 edge-groups x 80 lanes; pair-unrolled gather (round-3 structure).
__global__ __launch_bounds__(320) void k_agg_blk(const ushortT* __restrict__ h,
                                                 const float* __restrict__ alpha,
                                                 const float* __restrict__ rden,
                                                 const int* __restrict__ rowptr,
                                                 const int* __restrict__ ssrc,
                                                 const float* __restrict__ b1,
                                                 const float* __restrict__ b2,
                                                 ushortT* __restrict__ out) {
  int dnode = blockIdx.x;
  int t = threadIdx.x;
  int grp = t / 80;         // 0..3 edge group
  int r = t - grp * 80;     // position in row; ch0 = r*8
  int ch0 = r * 8;
  int head = (ch0 < 512) ? (ch0 >> 7) : (4 + ((ch0 - 512) >> 6));
  int e0 = rowptr[dnode], deg = rowptr[dnode + 1] - e0;
  float acc[8] = {};
  __shared__ float s_alpha[64 * 6];
  __shared__ int s_src[64];
  __shared__ float s_part[4][640];
  for (int base = 0; base < deg; base += 64) {
    int cnt = min(64, deg - base);
    __syncthreads();
    for (int tix = t; tix < cnt * 6; tix += 320)
      s_alpha[tix] = alpha[(size_t)(e0 + base) * 6 + tix];
    for (int tix = t; tix < cnt; tix += 320)
      s_src[tix] = ssrc[e0 + base + tix];
    __syncthreads();
    int jj = grp;
    for (; jj + 4 < cnt; jj += 8) {
      int sA = s_src[jj], sB = s_src[jj + 4];
      uint4 uA = *reinterpret_cast<const uint4*>(h + (size_t)sA * 640 + ch0);
      uint4 uB = *reinterpret_cast<const uint4*>(h + (size_t)sB * 640 + ch0);
      acc8(acc, uA, s_alpha[jj * 6 + head]);
      acc8(acc, uB, s_alpha[(jj + 4) * 6 + head]);
    }
    if (jj < cnt) {
      int sA = s_src[jj];
      uint4 uA = *reinterpret_cast<const uint4*>(h + (size_t)sA * 640 + ch0);
      acc8(acc, uA, s_alpha[jj * 6 + head]);
    }
  }
  __syncthreads();
#pragma unroll
  for (int q = 0; q < 8; ++q) s_part[grp][ch0 + q] = acc[q];
  __syncthreads();
  {
    int ch = t * 2;
    int hh = (ch < 512) ? (ch >> 7) : (4 + ((ch - 512) >> 6));
    float rd = rden[dnode * 6 + hh];
    float v0 = s_part[0][ch] + s_part[1][ch] + s_part[2][ch] + s_part[3][ch];
    float v1 = s_part[0][ch + 1] + s_part[1][ch + 1] + s_part[2][ch + 1] + s_part[3][ch + 1];
    v0 *= rd; v1 *= rd;
    v0 += (ch < 512) ? b1[ch] : b2[ch - 512];
    v1 += (ch < 512) ? b1[ch + 1] : b2[ch - 511];
    v0 = elu_f(v0); v1 = elu_f(v1);
    uintT o = (uintT)f2bfu(v0) | ((uintT)f2bfu(v1) << 16);
    *reinterpret_cast<uintT*>(&out[(size_t)dnode * 640 + ch]) = o;
  }
}

// ---------------- aggregate (mean over 8 heads), h bf16 -> out fp32 ---------
// 2 edge-groups x 128 lanes; pair-unrolled gather (round-3 structure).
__global__ __launch_bounds__(256) void k_agg_mean(
    const ushortT* __restrict__ h, const float* __restrict__ alpha,
    const float* __restrict__ rden,
    const int* __restrict__ rowptr, const int* __restrict__ ssrc,
    const float* __restrict__ bias, float* __restrict__ out) {
  int dnode = blockIdx.x;
  int t = threadIdx.x;
  int grp = t >> 7;        // 0..1 edge group
  int r = t & 127;         // position in row; ch0 = r*8
  int head = r >> 4;
  int e0 = rowptr[dnode], deg = rowptr[dnode + 1] - e0;
  float acc[8] = {};
  __shared__ float s_alpha[64 * 8];
  __shared__ int s_src[64];
  __shared__ float s_part[2][1024];
  for (int base = 0; base < deg; base += 64) {
    int cnt = min(64, deg - base);
    __syncthreads();
    for (int tix = t; tix < cnt * 8; tix += 256)
      s_alpha[tix] = alpha[(size_t)(e0 + base) * 8 + tix];
    for (int tix = t; tix < cnt; tix += 256)
      s_src[tix] = ssrc[e0 + base + tix];
    __syncthreads();
    int jj = grp;
    for (; jj + 2 < cnt; jj += 4) {
      int sA = s_src[jj], sB = s_src[jj + 2];
      uint4 uA = *reinterpret_cast<const uint4*>(h + (size_t)sA * 1024 + r * 8);
      uint4 uB = *reinterpret_cast<const uint4*>(h + (size_t)sB * 1024 + r * 8);
      acc8(acc, uA, s_alpha[jj * 8 + head]);
      acc8(acc, uB, s_alpha[(jj + 2) * 8 + head]);
    }
    if (jj < cnt) {
      int sA = s_src[jj];
      uint4 uA = *reinterpret_cast<const uint4*>(h + (size_t)sA * 1024 + r * 8);
      acc8(acc, uA, s_alpha[jj * 8 + head]);
    }
  }
  __syncthreads();
#pragma unroll
  for (int q = 0; q < 8; ++q) s_part[grp][r * 8 + q] = acc[q];
  __syncthreads();
  if (t < 128) {
    float v = 0.f;
#pragma unroll
    for (int hh = 0; hh < 8; ++hh) {
      float ph = s_part[0][hh * 128 + t] + s_part[1][hh * 128 + t];
      v += ph * rden[dnode * 8 + hh];
    }
    out[(size_t)dnode * 128 + t] = v * 0.125f + bias[t];
  }
}

// ---------------- launch ----------------
extern "C" void kernel_launch(void* const* d_in, const int* in_sizes, int n_in,
                              void* d_out, int out_size, void* d_ws, size_t ws_size,
                              hipStream_t stream) {
  const float* x_in   = (const float*)d_in[0];
  const int*   ei     = (const int*)d_in[1];
  const float* proj_W = (const float*)d_in[2];
  const float* proj_b = (const float*)d_in[3];
  const float* bng    = (const float*)d_in[4];
  const float* bnb    = (const float*)d_in[5];
  const float* g1W    = (const float*)d_in[6];
  const float* g1as   = (const float*)d_in[7];
  const float* g1ad   = (const float*)d_in[8];
  const float* g1b    = (const float*)d_in[9];
  const float* g2W    = (const float*)d_in[10];
  const float* g2as   = (const float*)d_in[11];
  const float* g2ad   = (const float*)d_in[12];
  const float* g2b    = (const float*)d_in[13];
  const float* uniW   = (const float*)d_in[14];
  const float* unib   = (const float*)d_in[15];
  const float* fing   = (const float*)d_in[16];
  const float* finb   = (const float*)d_in[17];
  const float* fgW    = (const float*)d_in[18];
  const float* fgas   = (const float*)d_in[19];
  const float* fgad   = (const float*)d_in[20];
  const float* fgb    = (const float*)d_in[21];

  const int EE = EDGES + NN;
  char* ws = (char*)d_ws;
  size_t off = 0;
  auto alloc = [&](size_t bytes) -> void* {
    void* p = ws + off;
    off += (bytes + 255) & ~(size_t)255;
    return p;
  };
  float*   xA    = (float*)alloc((size_t)NN * 512 * 4);
  float*   xB    = (float*)alloc((size_t)NN * 512 * 4);
  ushortT* xn    = (ushortT*)alloc((size_t)MPAD * 512 * 2);
  ushortT* xinb  = (ushortT*)alloc((size_t)MPAD * 256 * 2);
  ushortT* hcat  = (ushortT*)alloc((size_t)NN * 640 * 2);     // g1|g2 outputs [N,640]
  ushortT* xc    = (ushortT*)alloc((size_t)MPAD * 640 * 2);   // o1|o2 [N,640]
  float*   asb   = (float*)alloc((size_t)NN * 8 * 4);         // contiguous pair
  float*   adb   = (float*)alloc((size_t)NN * 8 * 4);
  float*   denb  = (float*)alloc((size_t)NN * 8 * 4);
  float*   alphab= (float*)alloc((size_t)EE * 8 * 4);
  ushortT* projT = (ushortT*)alloc((size_t)512 * 256 * 2);
  ushortT* gcatT = (ushortT*)alloc((size_t)3 * 640 * 512 * 2);  // [640][512] per block
  ushortT* uniT  = (ushortT*)alloc((size_t)3 * 512 * 640 * 2);
  ushortT* fgT   = (ushortT*)alloc((size_t)1024 * 512 * 2);
  int* cnt    = (int*)alloc((size_t)NN * 4);
  int* ptr    = (int*)alloc((size_t)(NN + 1) * 4);
  int* cursor = (int*)alloc((size_t)NN * 4);
  int* ssrc   = (int*)alloc((size_t)EE * 4);
  int* bsum   = (int*)alloc((size_t)128 * 4);
  int* boff   = (int*)alloc((size_t)128 * 4);
  ushortT* hf = hcat;  // final [N,1024] bf16 = 41 MB aliases hcat+xc (51.4 MB)

  const int NB79 = (NN + 255) / 256;  // 79

  // CSR build
  hipMemsetAsync(cnt, 0, (size_t)NN * 4, stream);
  k_hist<<<(EE + 255) / 256, 256, 0, stream>>>(ei, cnt);
  k_scan1<<<NB79, 256, 0, stream>>>(cnt, bsum, NN);
  k_scan2<<<1, 64, 0, stream>>>(bsum, boff, NB79, ptr, NN);
  k_scan3<<<NB79, 256, 0, stream>>>(cnt, boff, ptr, cursor, NN);
  k_scatter<<<(EE + 255) / 256, 256, 0, stream>>>(ei, cursor, ssrc);

  // weight transpose+convert (g1|g2 fused into gcatT rows 0..511 | 512..639)
  {
    CvtArgs a;
    int t0 = 0;
    auto add = [&](int idx, const float* s, ushortT* d, int K, int N) {
      a.d[idx] = { s, d, K, N, t0 };
      t0 += (K / 32) * (N / 32);
    };
    add(0, proj_W, projT, 256, 512);
    for (int i = 0; i < 3; ++i)
      add(1 + i, g1W + (size_t)i * 512 * 512, gcatT + (size_t)i * 640 * 512, 512, 512);
    for (int i = 0; i < 3; ++i)
      add(4 + i, g2W + (size_t)i * 512 * 128, gcatT + (size_t)i * 640 * 512 + 512 * 512, 512, 128);
    for (int i = 0; i < 3; ++i)
      add(7 + i, uniW + (size_t)i * 640 * 512, uniT + (size_t)i * 512 * 640, 640, 512);
    add(10, fgW, fgT, 512, 1024);
    k_cvtT<<<t0, 256, 0, stream>>>(a);
  }
  k_cvtX<<<(NN * 256 / 4 + 255) / 256, 256, 0, stream>>>(x_in, xinb, NN * 256 / 4);

  const int GMP = 160;  // padded m-tiles (157 real)

  // proj: x = elu(x_in @ proj_W + proj_b)
  k_gemm<1, false, 4, 0><<<GMP * 4, 256, 0, stream>>>(
      xinb, projT, proj_b, nullptr, xA,
      nullptr, nullptr, nullptr, nullptr, nullptr, nullptr, NN, 512, 256);

  float* cur = xA;
  float* alt = xB;
  for (int i = 0; i < 3; ++i) {
    k_ln<<<NN, 256, 0, stream>>>(cur, bng + i * 512, bnb + i * 512, xn);
    hipMemsetAsync(asb, 0, (size_t)2 * NN * 8 * 4, stream);  // asb|adb contiguous
    // fused g1|g2 GEMM -> hcat [N,640] + attention logits into asb/adb
    k_gemm<0, true, 5, 1><<<GMP * 5, 256, 0, stream>>>(
        xn, gcatT + (size_t)i * 640 * 512, nullptr, nullptr, hcat,
        g1as + i * 512, g1ad + i * 512, g2as + i * 128, g2ad + i * 128,
        asb, adb, NN, 640, 512);
    // softmax (16-lane parallel) + aggregate
    k_soft16<6><<<NN / 16, 256, 0, stream>>>(asb, adb, ptr, ssrc, alphab, denb);
    k_agg_blk<<<NN, 320, 0, stream>>>(hcat, alphab, denb, ptr, ssrc,
                                      g1b + i * 512, g2b + i * 128, xc);
    // x = elu(res + xc @ uniW + unib)
    k_gemm<2, false, 4, 0><<<GMP * 4, 256, 0, stream>>>(
        xc, uniT + (size_t)i * 512 * 640, unib + i * 512, cur, alt,
        nullptr, nullptr, nullptr, nullptr, nullptr, nullptr, NN, 512, 640);
    float* tmp = cur; cur = alt; alt = tmp;
  }

  // final LN + GAT (heads=8, mean)
  k_ln<<<NN, 256, 0, stream>>>(cur, fing, finb, xn);
  hipMemsetAsync(asb, 0, (size_t)2 * NN * 8 * 4, stream);
  k_gemm<0, true, 8, 2><<<GMP * 8, 256, 0, stream>>>(
      xn, fgT, nullptr, nullptr, hf,
      fgas, fgad, nullptr, nullptr, asb, adb, NN, 1024, 512);
  k_soft16<8><<<NN / 16, 256, 0, stream>>>(asb, adb, ptr, ssrc, alphab, denb);
  k_agg_mean<<<NN, 256, 0, stream>>>(hf, alphab, denb, ptr, ssrc, fgb, (float*)d_out);
}

// Round 7
// 684.517 us; speedup vs baseline: 1.2221x; 1.1085x over previous
//
#include <hip/hip_runtime.h>
#include <math.h>

#define NN 20000
#define EDGES 200000
#define MPAD 20096  // 157*128 — A-side GEMM buffers padded to full tiles

using short8  = __attribute__((ext_vector_type(8))) short;
using short4v = __attribute__((ext_vector_type(4))) short;
using f32x4   = __attribute__((ext_vector_type(4))) float;
typedef unsigned short ushortT;
typedef unsigned int uintT;

__device__ __forceinline__ ushortT f2bfu(float x) {
  union { float f; unsigned u; } c; c.f = x;
  unsigned r = c.u + 0x7FFFu + ((c.u >> 16) & 1u);
  return (ushortT)(r >> 16);
}
__device__ __forceinline__ float bflo(uintT u) {
  union { unsigned i; float f; } c; c.i = u << 16; return c.f;
}
__device__ __forceinline__ float bfhi(uintT u) {
  union { unsigned i; float f; } c; c.i = u & 0xFFFF0000u; return c.f;
}
__device__ __forceinline__ float elu_f(float v) { return v > 0.f ? v : (expf(v) - 1.f); }

__device__ __forceinline__ void acc8(float* acc, uint4 u, float a) {
  acc[0] += a * bflo(u.x); acc[1] += a * bfhi(u.x);
  acc[2] += a * bflo(u.y); acc[3] += a * bfhi(u.y);
  acc[4] += a * bflo(u.z); acc[5] += a * bfhi(u.z);
  acc[6] += a * bflo(u.w); acc[7] += a * bfhi(u.w);
}

// ---------------- CSR build ----------------
__global__ void k_hist(const int* __restrict__ ei, int* __restrict__ cnt) {
  int i = blockIdx.x * 256 + threadIdx.x;
  const int EE = EDGES + NN;
  if (i >= EE) return;
  int d = (i < EDGES) ? ei[EDGES + i] : (i - EDGES);
  atomicAdd(&cnt[d], 1);
}

__global__ __launch_bounds__(256) void k_scan1(const int* __restrict__ cnt,
                                               int* __restrict__ bsum, int n) {
  int b = blockIdx.x, t = threadIdx.x, i = b * 256 + t;
  int v = (i < n) ? cnt[i] : 0;
#pragma unroll
  for (int off = 32; off > 0; off >>= 1) v += __shfl_down(v, off);
  __shared__ int s[4];
  if ((t & 63) == 0) s[t >> 6] = v;
  __syncthreads();
  if (t == 0) bsum[b] = s[0] + s[1] + s[2] + s[3];
}

__global__ void k_scan2(const int* __restrict__ bsum, int* __restrict__ boff,
                        int nb, int* __restrict__ ptr, int n) {
  if (threadIdx.x == 0) {
    int acc = 0;
    for (int b = 0; b < nb; ++b) { boff[b] = acc; acc += bsum[b]; }
    ptr[n] = acc;
  }
}

__global__ __launch_bounds__(256) void k_scan3(const int* __restrict__ cnt,
                                               const int* __restrict__ boff,
                                               int* __restrict__ ptr,
                                               int* __restrict__ cursor, int n) {
  __shared__ int sd[256];
  int b = blockIdx.x, t = threadIdx.x, i = b * 256 + t;
  int v = (i < n) ? cnt[i] : 0;
  sd[t] = v;
  __syncthreads();
  for (int off = 1; off < 256; off <<= 1) {
    int a = (t >= off) ? sd[t - off] : 0;
    __syncthreads();
    sd[t] += a;
    __syncthreads();
  }
  if (i < n) {
    int p = boff[b] + sd[t] - v;  // exclusive
    ptr[i] = p;
    cursor[i] = p;
  }
}

__global__ void k_scatter(const int* __restrict__ ei, int* __restrict__ cursor,
                          int* __restrict__ ssrc) {
  int i = blockIdx.x * 256 + threadIdx.x;
  const int EE = EDGES + NN;
  if (i >= EE) return;
  int s, d;
  if (i < EDGES) { s = ei[i]; d = ei[EDGES + i]; }
  else           { s = i - EDGES; d = s; }
  int pos = atomicAdd(&cursor[d], 1);
  ssrc[pos] = s;
}

// ---------------- weight convert + transpose: W[K][N] f32 -> Wt[N][K] bf16 ----
struct CvtDesc { const float* src; ushortT* dst; int K; int N; int t0; };
struct CvtArgs { CvtDesc d[11]; };

__global__ __launch_bounds__(256) void k_cvtT(CvtArgs a) {
  __shared__ float tile[32][33];
  int b = blockIdx.x;
  int mi = 0;
#pragma unroll
  for (int i = 1; i < 11; ++i)
    if (b >= a.d[i].t0) mi = i;
  CvtDesc dd = a.d[mi];
  int tb = b - dd.t0;
  int tnc = dd.N / 32;
  int tk = tb / tnc, tn = tb % tnc;
  int t = threadIdx.x;
  {
    int r = t >> 3, c4 = (t & 7) * 4;
    float4 v = *reinterpret_cast<const float4*>(&dd.src[(size_t)(tk * 32 + r) * dd.N + tn * 32 + c4]);
    tile[r][c4 + 0] = v.x; tile[r][c4 + 1] = v.y; tile[r][c4 + 2] = v.z; tile[r][c4 + 3] = v.w;
  }
  __syncthreads();
  {
    int n = t >> 3, k4 = (t & 7) * 4;
    short4v s;
    s.x = (short)f2bfu(tile[k4 + 0][n]);
    s.y = (short)f2bfu(tile[k4 + 1][n]);
    s.z = (short)f2bfu(tile[k4 + 2][n]);
    s.w = (short)f2bfu(tile[k4 + 3][n]);
    *reinterpret_cast<short4v*>(&dd.dst[(size_t)(tn * 32 + n) * dd.K + tk * 32 + k4]) = s;
  }
}

// ---------------- x_in fp32 -> bf16 ----------------
__global__ void k_cvtX(const float* __restrict__ in, ushortT* __restrict__ out, int n4) {
  int i = blockIdx.x * 256 + threadIdx.x;
  if (i >= n4) return;
  float4 v = reinterpret_cast<const float4*>(in)[i];
  short4v s;
  s.x = (short)f2bfu(v.x); s.y = (short)f2bfu(v.y);
  s.z = (short)f2bfu(v.z); s.w = (short)f2bfu(v.w);
  reinterpret_cast<short4v*>(out)[i] = s;
}

// ---------------- LayerNorm (D=512), fp32 in -> bf16 out ----------------
__global__ __launch_bounds__(256) void k_ln(const float* __restrict__ in,
                                            const float* __restrict__ g,
                                            const float* __restrict__ b,
                                            ushortT* __restrict__ out) {
  int row = blockIdx.x, t = threadIdx.x;
  const float* r = in + (size_t)row * 512;
  float v0 = r[t], v1 = r[t + 256];
  __shared__ float red[4];
  int w = t >> 6, lane = t & 63;
  float s = v0 + v1;
#pragma unroll
  for (int off = 32; off > 0; off >>= 1) s += __shfl_down(s, off);
  if (lane == 0) red[w] = s;
  __syncthreads();
  float mu = (red[0] + red[1] + red[2] + red[3]) * (1.f / 512.f);
  float d0 = v0 - mu, d1 = v1 - mu;
  float vs = d0 * d0 + d1 * d1;
#pragma unroll
  for (int off = 32; off > 0; off >>= 1) vs += __shfl_down(vs, off);
  __syncthreads();
  if (lane == 0) red[w] = vs;
  __syncthreads();
  float var = (red[0] + red[1] + red[2] + red[3]) * (1.f / 512.f);
  float rs = rsqrtf(var + 1e-5f);
  ushortT* o = out + (size_t)row * 512;
  o[t]       = f2bfu(d0 * rs * g[t]       + b[t]);
  o[t + 256] = f2bfu(d1 * rs * g[t + 256] + b[t + 256]);
}

// ---------------- GEMM: Out[M,N] = A[M,K] @ Wt[N,K]^T  (bf16 MFMA) ----------
// 128x128 tile, 4 waves (2x2), reg double-buffered staging, XCD-affinity grid.
// EPI: 0 = plain, 1 = elu(acc + bias), 2 = elu(res + acc + bias)
// ATT: 0 = none; 1 = fused 6-head attention logits; 2 = fused 8-head.
//      Key geometry: every (row, head) is produced entirely within ONE block
//      (head blocks are 128/64-wide and aligned to n-tiles / wave strips), so
//      the two wave strips reduce through LDS and store DIRECTLY — no
//      atomics, no pre-zero memset. (round-6 atomic version: +20MB write-
//      through + tail drain; this removes it.)
template <int EPI, bool OUTBF16, int NB, int ATT>
__global__ __launch_bounds__(256) void k_gemm(const ushortT* __restrict__ A,
                                              const ushortT* __restrict__ Wt,
                                              const float* __restrict__ bias,
                                              const float* __restrict__ res,
                                              void* __restrict__ Outv,
                                              const float* __restrict__ w1s,
                                              const float* __restrict__ w1d,
                                              const float* __restrict__ w2s,
                                              const float* __restrict__ w2d,
                                              float* __restrict__ as_out,
                                              float* __restrict__ ad_out,
                                              int M, int N, int K) {
  __shared__ short As[128][40];
  __shared__ short Bs[128][40];
  int b = blockIdx.x;
  int x = b & 7, g = b >> 3;
  int mt = x + 8 * (g / NB);
  int nt = g % NB;
  int m0 = mt * 128, n0 = nt * 128;
  if (m0 >= M) return;
  int t = threadIdx.x;
  int w = t >> 6, lane = t & 63;
  int wm = w >> 1, wn = w & 1;
  int lr = lane & 15, lk = (lane >> 4) * 8;
  int sr = t >> 2, sc = (t & 3) * 8;   // staging: rows sr, sr+64; k-chunk sc
  int ga0 = m0 + sr, ga1 = m0 + sr + 64;
  const short8 z8 = {};

  short8 vA0, vA1, vB0, vB1;
  {
    vA0 = (ga0 < M) ? *reinterpret_cast<const short8*>(&A[(size_t)ga0 * K + sc]) : z8;
    vA1 = (ga1 < M) ? *reinterpret_cast<const short8*>(&A[(size_t)ga1 * K + sc]) : z8;
    vB0 = *reinterpret_cast<const short8*>(&Wt[(size_t)(n0 + sr) * K + sc]);
    vB1 = *reinterpret_cast<const short8*>(&Wt[(size_t)(n0 + sr + 64) * K + sc]);
  }
  f32x4 acc[4][4] = {};
  for (int k0 = 0; k0 < K; k0 += 32) {
    *reinterpret_cast<short8*>(&As[sr][sc]) = vA0;
    *reinterpret_cast<short8*>(&As[sr + 64][sc]) = vA1;
    *reinterpret_cast<short8*>(&Bs[sr][sc]) = vB0;
    *reinterpret_cast<short8*>(&Bs[sr + 64][sc]) = vB1;
    __syncthreads();
    int k1 = k0 + 32;
    if (k1 < K) {
      vA0 = (ga0 < M) ? *reinterpret_cast<const short8*>(&A[(size_t)ga0 * K + k1 + sc]) : z8;
      vA1 = (ga1 < M) ? *reinterpret_cast<const short8*>(&A[(size_t)ga1 * K + k1 + sc]) : z8;
      vB0 = *reinterpret_cast<const short8*>(&Wt[(size_t)(n0 + sr) * K + k1 + sc]);
      vB1 = *reinterpret_cast<const short8*>(&Wt[(size_t)(n0 + sr + 64) * K + k1 + sc]);
    }
    short8 af[4], bf[4];
#pragma unroll
    for (int m = 0; m < 4; ++m)
      af[m] = *reinterpret_cast<const short8*>(&As[wm * 64 + m * 16 + lr][lk]);
#pragma unroll
    for (int n = 0; n < 4; ++n)
      bf[n] = *reinterpret_cast<const short8*>(&Bs[wn * 64 + n * 16 + lr][lk]);
#pragma unroll
    for (int m = 0; m < 4; ++m)
#pragma unroll
      for (int n = 0; n < 4; ++n)
        acc[m][n] = __builtin_amdgcn_mfma_f32_16x16x32_bf16(af[m], bf[n], acc[m][n], 0, 0, 0);
    __syncthreads();
  }
  // store
#pragma unroll
  for (int m = 0; m < 4; ++m) {
#pragma unroll
    for (int n = 0; n < 4; ++n) {
#pragma unroll
      for (int j = 0; j < 4; ++j) {
        int row = wm * 64 + m * 16 + (lane >> 4) * 4 + j;
        int col = wn * 64 + n * 16 + lr;
        int gr = m0 + row, gc = n0 + col;
        if (gr < M) {
          float v = acc[m][n][j];
          if (EPI >= 1) v += bias[gc];
          if (EPI == 2) v += res[(size_t)gr * N + gc];
          if (EPI >= 1) v = elu_f(v);
          if (OUTBF16) ((ushortT*)Outv)[(size_t)gr * N + gc] = f2bfu(v);
          else         ((float*)Outv)[(size_t)gr * N + gc] = v;
        }
      }
    }
  }
  // fused attention logits: strip-reduce through LDS, direct store
  if (ATT) {
    __shared__ float s_as[2][128];
    __shared__ float s_ad[2][128];
    float wsv[4], wdv[4];
#pragma unroll
    for (int n = 0; n < 4; ++n) {
      int gc = n0 + wn * 64 + n * 16 + lr;
      if (ATT == 1) {
        wsv[n] = (gc < 512) ? w1s[gc] : w2s[gc - 512];
        wdv[n] = (gc < 512) ? w1d[gc] : w2d[gc - 512];
      } else {
        wsv[n] = w1s[gc];
        wdv[n] = w1d[gc];
      }
    }
#pragma unroll
    for (int m = 0; m < 4; ++m) {
#pragma unroll
      for (int j = 0; j < 4; ++j) {
        float sa = 0.f, da = 0.f;
#pragma unroll
        for (int n = 0; n < 4; ++n) {
          float v = acc[m][n][j];
          sa += v * wsv[n];
          da += v * wdv[n];
        }
#pragma unroll
        for (int o = 1; o < 16; o <<= 1) {
          sa += __shfl_xor(sa, o, 16);
          da += __shfl_xor(da, o, 16);
        }
        if (lr == 0) {
          int row = wm * 64 + m * 16 + (lane >> 4) * 4 + j;
          s_as[wn][row] = sa;
          s_ad[wn][row] = da;
        }
      }
    }
    __syncthreads();
    if (t < 128) {
      int gr = m0 + t;
      if (gr < M) {
        const int H = (ATT == 1) ? 6 : 8;
        if (ATT == 1 && nt == 4) {
          // tile 4 holds two 64-wide heads: strip0 -> head4, strip1 -> head5
          as_out[gr * H + 4] = s_as[0][t];
          ad_out[gr * H + 4] = s_ad[0][t];
          as_out[gr * H + 5] = s_as[1][t];
          ad_out[gr * H + 5] = s_ad[1][t];
        } else {
          // 128-wide head == this n-tile; both strips sum
          as_out[gr * H + nt] = s_as[0][t] + s_as[1][t];
          ad_out[gr * H + nt] = s_ad[0][t] + s_ad[1][t];
        }
      }
    }
  }
}

// ---------------- per-dst softmax -> unnormalized exp + 1/den --------------
// 4 nodes/wave, 16 nodes/block; 16-lane-parallel (round-3 structure).
template <int H>
__global__ __launch_bounds__(256) void k_soft16(const float* __restrict__ as_n,
                                                const float* __restrict__ ad_n,
                                                const int* __restrict__ rowptr,
                                                const int* __restrict__ ssrc,
                                                float* __restrict__ alpha,
                                                float* __restrict__ rden_out) {
  int t = threadIdx.x;
  int grp16 = t >> 4;       // 0..15 within block
  int l = t & 15;
  int dnode = blockIdx.x * 16 + grp16;
  int e0 = rowptr[dnode], deg = rowptr[dnode + 1] - e0;
  float adv[H], m[H], den[H];
#pragma unroll
  for (int hh = 0; hh < H; ++hh) {
    adv[hh] = ad_n[dnode * H + hh];
    m[hh] = -INFINITY;
    den[hh] = 0.f;
  }
  // pass 1: per-head max
  for (int base = 0; base < deg; base += 16) {
    int j = base + l;
    float e[H];
    if (j < deg) {
      int s = ssrc[e0 + j];
#pragma unroll
      for (int hh = 0; hh < H; ++hh) {
        float v = as_n[s * H + hh] + adv[hh];
        e[hh] = v > 0.f ? v : 0.2f * v;
      }
    } else {
#pragma unroll
      for (int hh = 0; hh < H; ++hh) e[hh] = -INFINITY;
    }
#pragma unroll
    for (int hh = 0; hh < H; ++hh) {
      float v = e[hh];
#pragma unroll
      for (int o = 8; o > 0; o >>= 1) v = fmaxf(v, __shfl_xor(v, o, 16));
      m[hh] = fmaxf(m[hh], v);
    }
  }
  // pass 2: exp + den, store exp to alpha (unnormalized)
  for (int base = 0; base < deg; base += 16) {
    int j = base + l;
    float p[H];
    if (j < deg) {
      int s = ssrc[e0 + j];
#pragma unroll
      for (int hh = 0; hh < H; ++hh) {
        float v = as_n[s * H + hh] + adv[hh];
        v = v > 0.f ? v : 0.2f * v;
        p[hh] = expf(v - m[hh]);
        alpha[(size_t)(e0 + j) * H + hh] = p[hh];
      }
    } else {
#pragma unroll
      for (int hh = 0; hh < H; ++hh) p[hh] = 0.f;
    }
#pragma unroll
    for (int hh = 0; hh < H; ++hh) {
      float v = p[hh];
#pragma unroll
      for (int o = 8; o > 0; o >>= 1) v += __shfl_xor(v, o, 16);
      den[hh] += v;
    }
  }
  if (l == 0) {
#pragma unroll
    for (int hh = 0; hh < H; ++hh)
      rden_out[dnode * H + hh] = 1.f / den[hh];
  }
}

// ---------------- fused per-layer aggregate: 640 ch, 6 heads, elu ----------
// 4 edge-groups x 80 lanes; pair-unrolled gather (round-3 structure).
__global__ __launch_bounds__(320) void k_agg_blk(const ushortT* __restrict__ h,
                                                 const float* __restrict__ alpha,
                                                 const float* __restrict__ rden,
                                                 const int* __restrict__ rowptr,
                                                 const int* __restrict__ ssrc,
                                                 const float* __restrict__ b1,
                                                 const float* __restrict__ b2,
                                                 ushortT* __restrict__ out) {
  int dnode = blockIdx.x;
  int t = threadIdx.x;
  int grp = t / 80;         // 0..3 edge group
  int r = t - grp * 80;     // position in row; ch0 = r*8
  int ch0 = r * 8;
  int head = (ch0 < 512) ? (ch0 >> 7) : (4 + ((ch0 - 512) >> 6));
  int e0 = rowptr[dnode], deg = rowptr[dnode + 1] - e0;
  float acc[8] = {};
  __shared__ float s_alpha[64 * 6];
  __shared__ int s_src[64];
  __shared__ float s_part[4][640];
  for (int base = 0; base < deg; base += 64) {
    int cnt = min(64, deg - base);
    __syncthreads();
    for (int tix = t; tix < cnt * 6; tix += 320)
      s_alpha[tix] = alpha[(size_t)(e0 + base) * 6 + tix];
    for (int tix = t; tix < cnt; tix += 320)
      s_src[tix] = ssrc[e0 + base + tix];
    __syncthreads();
    int jj = grp;
    for (; jj + 4 < cnt; jj += 8) {
      int sA = s_src[jj], sB = s_src[jj + 4];
      uint4 uA = *reinterpret_cast<const uint4*>(h + (size_t)sA * 640 + ch0);
      uint4 uB = *reinterpret_cast<const uint4*>(h + (size_t)sB * 640 + ch0);
      acc8(acc, uA, s_alpha[jj * 6 + head]);
      acc8(acc, uB, s_alpha[(jj + 4) * 6 + head]);
    }
    if (jj < cnt) {
      int sA = s_src[jj];
      uint4 uA = *reinterpret_cast<const uint4*>(h + (size_t)sA * 640 + ch0);
      acc8(acc, uA, s_alpha[jj * 6 + head]);
    }
  }
  __syncthreads();
#pragma unroll
  for (int q = 0; q < 8; ++q) s_part[grp][ch0 + q] = acc[q];
  __syncthreads();
  {
    int ch = t * 2;
    int hh = (ch < 512) ? (ch >> 7) : (4 + ((ch - 512) >> 6));
    float rd = rden[dnode * 6 + hh];
    float v0 = s_part[0][ch] + s_part[1][ch] + s_part[2][ch] + s_part[3][ch];
    float v1 = s_part[0][ch + 1] + s_part[1][ch + 1] + s_part[2][ch + 1] + s_part[3][ch + 1];
    v0 *= rd; v1 *= rd;
    v0 += (ch < 512) ? b1[ch] : b2[ch - 512];
    v1 += (ch < 512) ? b1[ch + 1] : b2[ch - 511];
    v0 = elu_f(v0); v1 = elu_f(v1);
    uintT o = (uintT)f2bfu(v0) | ((uintT)f2bfu(v1) << 16);
    *reinterpret_cast<uintT*>(&out[(size_t)dnode * 640 + ch]) = o;
  }
}

// ---------------- aggregate (mean over 8 heads), h bf16 -> out fp32 ---------
// 2 edge-groups x 128 lanes; pair-unrolled gather (round-3 structure).
__global__ __launch_bounds__(256) void k_agg_mean(
    const ushortT* __restrict__ h, const float* __restrict__ alpha,
    const float* __restrict__ rden,
    const int* __restrict__ rowptr, const int* __restrict__ ssrc,
    const float* __restrict__ bias, float* __restrict__ out) {
  int dnode = blockIdx.x;
  int t = threadIdx.x;
  int grp = t >> 7;        // 0..1 edge group
  int r = t & 127;         // position in row; ch0 = r*8
  int head = r >> 4;
  int e0 = rowptr[dnode], deg = rowptr[dnode + 1] - e0;
  float acc[8] = {};
  __shared__ float s_alpha[64 * 8];
  __shared__ int s_src[64];
  __shared__ float s_part[2][1024];
  for (int base = 0; base < deg; base += 64) {
    int cnt = min(64, deg - base);
    __syncthreads();
    for (int tix = t; tix < cnt * 8; tix += 256)
      s_alpha[tix] = alpha[(size_t)(e0 + base) * 8 + tix];
    for (int tix = t; tix < cnt; tix += 256)
      s_src[tix] = ssrc[e0 + base + tix];
    __syncthreads();
    int jj = grp;
    for (; jj + 2 < cnt; jj += 4) {
      int sA = s_src[jj], sB = s_src[jj + 2];
      uint4 uA = *reinterpret_cast<const uint4*>(h + (size_t)sA * 1024 + r * 8);
      uint4 uB = *reinterpret_cast<const uint4*>(h + (size_t)sB * 1024 + r * 8);
      acc8(acc, uA, s_alpha[jj * 8 + head]);
      acc8(acc, uB, s_alpha[(jj + 2) * 8 + head]);
    }
    if (jj < cnt) {
      int sA = s_src[jj];
      uint4 uA = *reinterpret_cast<const uint4*>(h + (size_t)sA * 1024 + r * 8);
      acc8(acc, uA, s_alpha[jj * 8 + head]);
    }
  }
  __syncthreads();
#pragma unroll
  for (int q = 0; q < 8; ++q) s_part[grp][r * 8 + q] = acc[q];
  __syncthreads();
  if (t < 128) {
    float v = 0.f;
#pragma unroll
    for (int hh = 0; hh < 8; ++hh) {
      float ph = s_part[0][hh * 128 + t] + s_part[1][hh * 128 + t];
      v += ph * rden[dnode * 8 + hh];
    }
    out[(size_t)dnode * 128 + t] = v * 0.125f + bias[t];
  }
}

// ---------------- launch ----------------
extern "C" void kernel_launch(void* const* d_in, const int* in_sizes, int n_in,
                              void* d_out, int out_size, void* d_ws, size_t ws_size,
                              hipStream_t stream) {
  const float* x_in   = (const float*)d_in[0];
  const int*   ei     = (const int*)d_in[1];
  const float* proj_W = (const float*)d_in[2];
  const float* proj_b = (const float*)d_in[3];
  const float* bng    = (const float*)d_in[4];
  const float* bnb    = (const float*)d_in[5];
  const float* g1W    = (const float*)d_in[6];
  const float* g1as   = (const float*)d_in[7];
  const float* g1ad   = (const float*)d_in[8];
  const float* g1b    = (const float*)d_in[9];
  const float* g2W    = (const float*)d_in[10];
  const float* g2as   = (const float*)d_in[11];
  const float* g2ad   = (const float*)d_in[12];
  const float* g2b    = (const float*)d_in[13];
  const float* uniW   = (const float*)d_in[14];
  const float* unib   = (const float*)d_in[15];
  const float* fing   = (const float*)d_in[16];
  const float* finb   = (const float*)d_in[17];
  const float* fgW    = (const float*)d_in[18];
  const float* fgas   = (const float*)d_in[19];
  const float* fgad   = (const float*)d_in[20];
  const float* fgb    = (const float*)d_in[21];

  const int EE = EDGES + NN;
  char* ws = (char*)d_ws;
  size_t off = 0;
  auto alloc = [&](size_t bytes) -> void* {
    void* p = ws + off;
    off += (bytes + 255) & ~(size_t)255;
    return p;
  };
  float*   xA    = (float*)alloc((size_t)NN * 512 * 4);
  float*   xB    = (float*)alloc((size_t)NN * 512 * 4);
  ushortT* xn    = (ushortT*)alloc((size_t)MPAD * 512 * 2);
  ushortT* xinb  = (ushortT*)alloc((size_t)MPAD * 256 * 2);
  ushortT* hcat  = (ushortT*)alloc((size_t)NN * 640 * 2);     // g1|g2 outputs [N,640]
  ushortT* xc    = (ushortT*)alloc((size_t)MPAD * 640 * 2);   // o1|o2 [N,640]
  float*   asb   = (float*)alloc((size_t)NN * 8 * 4);
  float*   adb   = (float*)alloc((size_t)NN * 8 * 4);
  float*   denb  = (float*)alloc((size_t)NN * 8 * 4);
  float*   alphab= (float*)alloc((size_t)EE * 8 * 4);
  ushortT* projT = (ushortT*)alloc((size_t)512 * 256 * 2);
  ushortT* gcatT = (ushortT*)alloc((size_t)3 * 640 * 512 * 2);  // [640][512] per block
  ushortT* uniT  = (ushortT*)alloc((size_t)3 * 512 * 640 * 2);
  ushortT* fgT   = (ushortT*)alloc((size_t)1024 * 512 * 2);
  int* cnt    = (int*)alloc((size_t)NN * 4);
  int* ptr    = (int*)alloc((size_t)(NN + 1) * 4);
  int* cursor = (int*)alloc((size_t)NN * 4);
  int* ssrc   = (int*)alloc((size_t)EE * 4);
  int* bsum   = (int*)alloc((size_t)128 * 4);
  int* boff   = (int*)alloc((size_t)128 * 4);
  ushortT* hf = hcat;  // final [N,1024] bf16 = 41 MB aliases hcat+xc (51.4 MB)

  const int NB79 = (NN + 255) / 256;  // 79

  // CSR build
  hipMemsetAsync(cnt, 0, (size_t)NN * 4, stream);
  k_hist<<<(EE + 255) / 256, 256, 0, stream>>>(ei, cnt);
  k_scan1<<<NB79, 256, 0, stream>>>(cnt, bsum, NN);
  k_scan2<<<1, 64, 0, stream>>>(bsum, boff, NB79, ptr, NN);
  k_scan3<<<NB79, 256, 0, stream>>>(cnt, boff, ptr, cursor, NN);
  k_scatter<<<(EE + 255) / 256, 256, 0, stream>>>(ei, cursor, ssrc);

  // weight transpose+convert (g1|g2 fused into gcatT rows 0..511 | 512..639)
  {
    CvtArgs a;
    int t0 = 0;
    auto add = [&](int idx, const float* s, ushortT* d, int K, int N) {
      a.d[idx] = { s, d, K, N, t0 };
      t0 += (K / 32) * (N / 32);
    };
    add(0, proj_W, projT, 256, 512);
    for (int i = 0; i < 3; ++i)
      add(1 + i, g1W + (size_t)i * 512 * 512, gcatT + (size_t)i * 640 * 512, 512, 512);
    for (int i = 0; i < 3; ++i)
      add(4 + i, g2W + (size_t)i * 512 * 128, gcatT + (size_t)i * 640 * 512 + 512 * 512, 512, 128);
    for (int i = 0; i < 3; ++i)
      add(7 + i, uniW + (size_t)i * 640 * 512, uniT + (size_t)i * 512 * 640, 640, 512);
    add(10, fgW, fgT, 512, 1024);
    k_cvtT<<<t0, 256, 0, stream>>>(a);
  }
  k_cvtX<<<(NN * 256 / 4 + 255) / 256, 256, 0, stream>>>(x_in, xinb, NN * 256 / 4);

  const int GMP = 160;  // padded m-tiles (157 real)

  // proj: x = elu(x_in @ proj_W + proj_b)
  k_gemm<1, false, 4, 0><<<GMP * 4, 256, 0, stream>>>(
      xinb, projT, proj_b, nullptr, xA,
      nullptr, nullptr, nullptr, nullptr, nullptr, nullptr, NN, 512, 256);

  float* cur = xA;
  float* alt = xB;
  for (int i = 0; i < 3; ++i) {
    k_ln<<<NN, 256, 0, stream>>>(cur, bng + i * 512, bnb + i * 512, xn);
    // fused g1|g2 GEMM -> hcat [N,640] + attention logits into asb/adb
    k_gemm<0, true, 5, 1><<<GMP * 5, 256, 0, stream>>>(
        xn, gcatT + (size_t)i * 640 * 512, nullptr, nullptr, hcat,
        g1as + i * 512, g1ad + i * 512, g2as + i * 128, g2ad + i * 128,
        asb, adb, NN, 640, 512);
    // softmax (16-lane parallel) + aggregate
    k_soft16<6><<<NN / 16, 256, 0, stream>>>(asb, adb, ptr, ssrc, alphab, denb);
    k_agg_blk<<<NN, 320, 0, stream>>>(hcat, alphab, denb, ptr, ssrc,
                                      g1b + i * 512, g2b + i * 128, xc);
    // x = elu(res + xc @ uniW + unib)
    k_gemm<2, false, 4, 0><<<GMP * 4, 256, 0, stream>>>(
        xc, uniT + (size_t)i * 512 * 640, unib + i * 512, cur, alt,
        nullptr, nullptr, nullptr, nullptr, nullptr, nullptr, NN, 512, 640);
    float* tmp = cur; cur = alt; alt = tmp;
  }

  // final LN + GAT (heads=8, mean)
  k_ln<<<NN, 256, 0, stream>>>(cur, fing, finb, xn);
  k_gemm<0, true, 8, 2><<<GMP * 8, 256, 0, stream>>>(
      xn, fgT, nullptr, nullptr, hf,
      fgas, fgad, nullptr, nullptr, asb, adb, NN, 1024, 512);
  k_soft16<8><<<NN / 16, 256, 0, stream>>>(asb, adb, ptr, ssrc, alphab, denb);
  k_agg_mean<<<NN, 256, 0, stream>>>(hf, alphab, denb, ptr, ssrc, fgb, (float*)d_out);
}